// Round 7
// baseline (237.864 us; speedup 1.0000x reference)
//
#include <hip/hip_runtime.h>

#define T_TOKENS 2048
#define N_EXPERTS 8
#define ROWS (T_TOKENS * 2)      // T * TOPK
#define I_DIM 2048
#define H_DIM 1024

#define M_TILE 128
#define N_TILE 128
#define BK 32
#define KSPLIT 2
#define KCHUNK (I_DIM / KSPLIT)  // 1024
#define NITER (KCHUNK / BK)      // 32
#define MAX_SLOTS 5120           // ROWS + 8*128 padding headroom
#define MAX_ZT (MAX_SLOTS / M_TILE)  // 40

typedef __bf16 bf16x8 __attribute__((ext_vector_type(8)));
typedef __bf16 bf16x4 __attribute__((ext_vector_type(4)));
typedef float f32x4 __attribute__((ext_vector_type(4)));

__device__ inline void load_lds16(const void* g, void* l) {
    // lane i's 16B -> (wave-uniform) l + i*16 ; global side CONTIGUOUS 1KB
    __builtin_amdgcn_global_load_lds(
        (const __attribute__((address_space(1))) void*)g,
        (__attribute__((address_space(3))) void*)l, 16, 0, 0);
}

__device__ inline void experts_off(const int* __restrict__ cnt, int* off) {
    off[0] = 0;
#pragma unroll
    for (int i = 0; i < 8; ++i)
        off[i + 1] = (off[i] + cnt[i] + 127) & ~127;   // 128-aligned segments
}

// Fused prep: (a) transpose+convert w [E][K][N] fp32 -> packed B tiles,
// (b) zero d_out, (c) routing (softmax + top-2 + per-expert rowlists).
// Packed-B: tile(e, nt, kb) = 4096 bf16; elem (n,k) at
//   u*512 + (quad*16 + (n&15))*8 + (k&7), u=(n&127)>>4, quad=(k>>3)&3.
__global__ __launch_bounds__(256) void prep_kernel(
    const float* __restrict__ w, __bf16* __restrict__ bp,
    float* __restrict__ out,
    const float* __restrict__ logits, float* __restrict__ topk_w,
    int* __restrict__ cnt, int* __restrict__ rowlist) {
    const int bx = blockIdx.x;
    const int t = threadIdx.x;
    if (bx >= 5120) {
        // routing: 8 blocks, one thread per token
        int tok = (bx - 5120) * 256 + t;
        if (tok >= T_TOKENS) return;
        float l[8];
#pragma unroll
        for (int e = 0; e < 8; ++e) l[e] = logits[tok * 8 + e];
        float mx = l[0];
#pragma unroll
        for (int e = 1; e < 8; ++e) mx = fmaxf(mx, l[e]);
        float s = 0.f;
#pragma unroll
        for (int e = 0; e < 8; ++e) { l[e] = expf(l[e] - mx); s += l[e]; }
        float inv = 1.f / s;
        float v0 = -1.f, v1 = -1.f; int i0 = 0, i1 = 0;
#pragma unroll
        for (int e = 0; e < 8; ++e) {
            float p = l[e] * inv;
            if (p > v0)      { v1 = v0; i1 = i0; v0 = p; i0 = e; }
            else if (p > v1) { v1 = p; i1 = e; }
        }
        topk_w[2 * tok]     = v0;
        topk_w[2 * tok + 1] = v1;
        int p0 = atomicAdd(&cnt[i0], 1); rowlist[i0 * ROWS + p0] = 2 * tok;
        int p1 = atomicAdd(&cnt[i1], 1); rowlist[i1 * ROWS + p1] = 2 * tok + 1;
        return;
    }
    if (bx >= 4096) {
        // zero out: 1024 blocks * 256 thr * 8 floats = 2M floats
        int idx = (bx - 4096) * 256 + t;
        f32x4 z = (f32x4){0.f, 0.f, 0.f, 0.f};
        ((f32x4*)out)[2 * idx] = z;
        ((f32x4*)out)[2 * idx + 1] = z;
        return;
    }
    __shared__ float tile[64 * 66];  // pitch 66 breaks bank conflicts
    const int e = bx >> 9;           // 512 blocks/expert = 32 ktiles * 16 ntiles
    const int k0 = ((bx >> 4) & 31) * 64;
    const int n0 = (bx & 15) * 64;
    const float* wsrc = w + (size_t)e * (I_DIM * H_DIM);
#pragma unroll
    for (int r = 0; r < 4; ++r) {
        int kl = (t >> 4) * 4 + r;
        int nl = (t & 15) * 4;
        f32x4 v = *(const f32x4*)(wsrc + (size_t)(k0 + kl) * H_DIM + n0 + nl);
        tile[kl * 66 + nl]     = v.x;
        tile[kl * 66 + nl + 1] = v.y;
        tile[kl * 66 + nl + 2] = v.z;
        tile[kl * 66 + nl + 3] = v.w;
    }
    __syncthreads();
    const int nt = n0 >> 7;
    __bf16* base = bp + (size_t)(e * 8 + nt) * 64 * 4096;
#pragma unroll
    for (int r = 0; r < 4; ++r) {
        int nl = (t >> 4) * 4 + r;
        int klc = (t & 15) * 4;
        int n_rel = nl & 15;
        int u = ((n0 & 127) + nl) >> 4;
        int kb = (k0 + klc) >> 5;
        int quad = (klc >> 3) & 3;
        int j0 = klc & 7;
        bf16x4 b = { (__bf16)tile[klc * 66 + nl],
                     (__bf16)tile[(klc + 1) * 66 + nl],
                     (__bf16)tile[(klc + 2) * 66 + nl],
                     (__bf16)tile[(klc + 3) * 66 + nl] };
        *(bf16x4*)&base[(size_t)kb * 4096 + u * 512 + (quad * 16 + n_rel) * 8 + j0] = b;
    }
}

// Pack A: gather routed rows -> bf16 tiles in fragment order.
// Slot space: expert segments 128-aligned. Tile(zt, kb) = 4096 bf16, 8 units.
// Wave = one 16-slot unit; lane l: m_rel=l&15, kq=l>>4; per kb: read 32B fp32,
// write 16B bf16 at unit*512 + lane*8 -> wave writes contiguous 1KB.
__global__ __launch_bounds__(256) void packa_kernel(
    const float* __restrict__ x, const int* __restrict__ cnt,
    const int* __restrict__ rowlist, __bf16* __restrict__ ap) {
    int off[9];
    experts_off(cnt, off);
    const int wave = threadIdx.x >> 6, lane = threadIdx.x & 63;
    const int gu = blockIdx.x * 4 + wave;   // global unit
    const int sb = gu * 16;
    if (sb >= off[8]) return;
    int e = 0;
#pragma unroll
    for (int i = 1; i < 8; ++i) if (sb >= off[i]) e = i;
    const int m_rel = lane & 15, kq = lane >> 4;
    const int local = sb - off[e] + m_rel;
    const bool valid = local < cnt[e];
    const float* src = x + (size_t)(valid ? rowlist[e * ROWS + local] : 0) * I_DIM + kq * 8;
    __bf16* dst = ap + (size_t)(sb >> 7) * 64 * 4096 + ((sb >> 4) & 7) * 512 + lane * 8;
#pragma unroll 4
    for (int kb = 0; kb < 64; ++kb) {
        f32x4 lo = *(const f32x4*)(src + kb * 32);
        f32x4 hi = *(const f32x4*)(src + kb * 32 + 4);
        bf16x8 v;
        if (valid) {
            v = (bf16x8){ (__bf16)lo.x, (__bf16)lo.y, (__bf16)lo.z, (__bf16)lo.w,
                          (__bf16)hi.x, (__bf16)hi.y, (__bf16)hi.z, (__bf16)hi.w };
        } else {
            v = (bf16x8){ (__bf16)0.f, (__bf16)0.f, (__bf16)0.f, (__bf16)0.f,
                          (__bf16)0.f, (__bf16)0.f, (__bf16)0.f, (__bf16)0.f };
        }
        *(bf16x8*)(dst + (size_t)kb * 4096) = v;
    }
}

// Grouped expert GEMM, 128x128 tile, bf16 MFMA 16x16x32.
// Both operands pre-packed bf16; ALL staging is contiguous-1KB global_load_lds
// (4 DMA/wave/iter), double-buffered, single barrier per iter. No gather, no
// cvt, near-zero VALU in the hot loop.
__global__ __launch_bounds__(256, 4) void gemm_kernel(
    const __bf16* __restrict__ ap, const __bf16* __restrict__ bp,
    const int* __restrict__ cnt, const int* __restrict__ rowlist,
    const float* __restrict__ topk_w, float* __restrict__ out) {
    int off[9];
    experts_off(cnt, off);
    const int zt = blockIdx.y;
    const int sb = zt * M_TILE;
    if (sb >= off[8]) return;
    int e = 0;
#pragma unroll
    for (int i = 1; i < 8; ++i) if (sb >= off[i]) e = i;
    const int cnt_e = cnt[e];
    const int lm0 = sb - off[e];
    if (lm0 >= cnt_e) return;   // all-padding tile
    const int ntile = blockIdx.x & 7;
    const int khalf = blockIdx.x >> 3;
    const int n0 = ntile * N_TILE;
    const int tid = threadIdx.x;
    const int lane = tid & 63;
    const int wave = tid >> 6;
    const int wm = wave & 1, wn = wave >> 1;

    __shared__ __bf16 As[2][M_TILE * BK];   // 2 x 8 KB
    __shared__ __bf16 Bs[2][N_TILE * BK];   // 2 x 8 KB

    // per-wave DMA: A units {2w,2w+1}, B units {2w,2w+1}
    const __bf16* a_src = ap + ((size_t)zt * 64 + khalf * 32) * 4096
                             + 2 * wave * 512 + lane * 8;
    const __bf16* b_src = bp + ((size_t)(e * 8 + ntile) * 64 + khalf * 32) * 4096
                             + 2 * wave * 512 + lane * 8;
    const int du = 2 * wave * 512;

    f32x4 acc[4][4];
#pragma unroll
    for (int mt = 0; mt < 4; ++mt)
#pragma unroll
        for (int nt = 0; nt < 4; ++nt)
            acc[mt][nt] = (f32x4){0.f, 0.f, 0.f, 0.f};

    // prologue: tile 0 -> buf 0
    load_lds16(a_src,       &As[0][du]);
    load_lds16(a_src + 512, &As[0][du + 512]);
    load_lds16(b_src,       &Bs[0][du]);
    load_lds16(b_src + 512, &Bs[0][du + 512]);

    for (int it = 0; it < NITER; ++it) {
        const int buf = it & 1;
        __syncthreads();   // drains tile-it DMA; buf^1 free
        if (it + 1 < NITER) {
            const __bf16* as = a_src + (size_t)(it + 1) * 4096;
            const __bf16* bs = b_src + (size_t)(it + 1) * 4096;
            load_lds16(as,       &As[buf ^ 1][du]);
            load_lds16(as + 512, &As[buf ^ 1][du + 512]);
            load_lds16(bs,       &Bs[buf ^ 1][du]);
            load_lds16(bs + 512, &Bs[buf ^ 1][du + 512]);
        }
        bf16x8 bfr[4], af[4];
#pragma unroll
        for (int nt = 0; nt < 4; ++nt)
            bfr[nt] = *(const bf16x8*)&Bs[buf][(wn * 4 + nt) * 512 + lane * 8];
#pragma unroll
        for (int mt = 0; mt < 4; ++mt)
            af[mt] = *(const bf16x8*)&As[buf][(wm * 4 + mt) * 512 + lane * 8];
#pragma unroll
        for (int mt = 0; mt < 4; ++mt)
#pragma unroll
            for (int nt = 0; nt < 4; ++nt)
                acc[mt][nt] = __builtin_amdgcn_mfma_f32_16x16x32_bf16(
                    af[mt], bfr[nt], acc[mt][nt], 0, 0, 0);
    }

    // epilogue: C/D col=lane&15, row=(lane>>4)*4+reg; scale by topk weight,
    // atomicAdd into out[token] (covers topk-sum and K-split sum)
    const int lq = lane >> 4, ln = lane & 15;
    const int* rl = rowlist + e * ROWS;
#pragma unroll
    for (int mt = 0; mt < 4; ++mt) {
#pragma unroll
        for (int j = 0; j < 4; ++j) {
            int local = lm0 + (wm * 4 + mt) * 16 + lq * 4 + j;
            if (local < cnt_e) {
                int row = rl[local];
                float tw = topk_w[row];
                float* orow = out + (size_t)(row >> 1) * H_DIM + n0 + wn * 64 + ln;
#pragma unroll
                for (int nt = 0; nt < 4; ++nt)
                    atomicAdd(&orow[nt * 16], acc[mt][nt][j] * tw);
            }
        }
    }
}

extern "C" void kernel_launch(void* const* d_in, const int* in_sizes, int n_in,
                              void* d_out, int out_size, void* d_ws, size_t ws_size,
                              hipStream_t stream) {
    const float* x      = (const float*)d_in[0];  // [ROWS, I_DIM] fp32
    const float* w      = (const float*)d_in[1];  // [E, I_DIM, H_DIM] fp32
    const float* logits = (const float*)d_in[2];  // [T, E] fp32
    float* out = (float*)d_out;                   // [T, H_DIM] fp32

    char* ws = (char*)d_ws;
    float*  topk_w  = (float*)ws;                             // 16 KB
    int*    cnt     = (int*)(ws + 16384);                     // 8 int (padded)
    int*    rowlist = (int*)(ws + 16384 + 128);               // 128 KB
    __bf16* bp      = (__bf16*)(ws + 16384 + 128 + 131072);   // packed B (32 MB)
    __bf16* ap      = (__bf16*)(ws + 16384 + 128 + 131072 + (size_t)32 * 1024 * 1024); // packed A (20 MB)

    hipMemsetAsync(cnt, 0, N_EXPERTS * sizeof(int), stream);
    // prep: B transpose+pack (4096) + out zero (1024) + routing (8)
    prep_kernel<<<5128, 256, 0, stream>>>(w, bp, out, logits, topk_w, cnt, rowlist);
    // pack A: 5120 slots / 64 per block
    packa_kernel<<<MAX_SLOTS / 64, 256, 0, stream>>>(x, cnt, rowlist, ap);
    // x = ntile+khalf (16, all active), y = m-tile (early-exit tail)
    gemm_kernel<<<dim3((H_DIM / N_TILE) * KSPLIT, MAX_ZT), 256, 0, stream>>>(
        ap, bp, cnt, rowlist, topk_w, out);
}

// Round 8
// 220.507 us; speedup vs baseline: 1.0787x; 1.0787x over previous
//
#include <hip/hip_runtime.h>

#define T_TOKENS 2048
#define N_EXPERTS 8
#define ROWS (T_TOKENS * 2)      // T * TOPK
#define I_DIM 2048
#define H_DIM 1024

#define M_TILE 128
#define N_TILE 128
#define BK 32
#define KSPLIT 2
#define KCHUNK (I_DIM / KSPLIT)  // 1024
#define NITER (KCHUNK / BK)      // 32
#define MAX_SLOTS 5120           // ROWS + 8*128 padding headroom
#define MAX_ZT (MAX_SLOTS / M_TILE)  // 40

typedef __bf16 bf16x8 __attribute__((ext_vector_type(8)));
typedef __bf16 bf16x4 __attribute__((ext_vector_type(4)));
typedef float f32x4 __attribute__((ext_vector_type(4)));

__device__ inline void load_lds16(const void* g, void* l) {
    // lane i's 16B -> (wave-uniform) l + i*16 ; global side CONTIGUOUS 1KB
    __builtin_amdgcn_global_load_lds(
        (const __attribute__((address_space(1))) void*)g,
        (__attribute__((address_space(3))) void*)l, 16, 0, 0);
}

__device__ inline void experts_off(const int* __restrict__ cnt, int* off) {
    off[0] = 0;
#pragma unroll
    for (int i = 0; i < 8; ++i)
        off[i + 1] = (off[i] + cnt[i] + 127) & ~127;   // 128-aligned segments
}

// Fused prep: (a) transpose+convert w [E][K][N] fp32 -> packed B tiles,
// (b) zero d_out, (c) routing (softmax + top-2 + per-expert rowlists).
// Packed-B: tile(e, nt, kb) = 4096 bf16; elem (n,k) at
//   u*512 + (quad*16 + (n&15))*8 + (k&7), u=(n&127)>>4, quad=(k>>3)&3.
__global__ __launch_bounds__(256) void prep_kernel(
    const float* __restrict__ w, __bf16* __restrict__ bp,
    float* __restrict__ out,
    const float* __restrict__ logits, float* __restrict__ topk_w,
    int* __restrict__ cnt, int* __restrict__ rowlist) {
    const int bx = blockIdx.x;
    const int t = threadIdx.x;
    if (bx >= 5120) {
        // routing: 8 blocks, one thread per token
        int tok = (bx - 5120) * 256 + t;
        if (tok >= T_TOKENS) return;
        float l[8];
#pragma unroll
        for (int e = 0; e < 8; ++e) l[e] = logits[tok * 8 + e];
        float mx = l[0];
#pragma unroll
        for (int e = 1; e < 8; ++e) mx = fmaxf(mx, l[e]);
        float s = 0.f;
#pragma unroll
        for (int e = 0; e < 8; ++e) { l[e] = expf(l[e] - mx); s += l[e]; }
        float inv = 1.f / s;
        float v0 = -1.f, v1 = -1.f; int i0 = 0, i1 = 0;
#pragma unroll
        for (int e = 0; e < 8; ++e) {
            float p = l[e] * inv;
            if (p > v0)      { v1 = v0; i1 = i0; v0 = p; i0 = e; }
            else if (p > v1) { v1 = p; i1 = e; }
        }
        topk_w[2 * tok]     = v0;
        topk_w[2 * tok + 1] = v1;
        int p0 = atomicAdd(&cnt[i0], 1); rowlist[i0 * ROWS + p0] = 2 * tok;
        int p1 = atomicAdd(&cnt[i1], 1); rowlist[i1 * ROWS + p1] = 2 * tok + 1;
        return;
    }
    if (bx >= 4096) {
        // zero out: 1024 blocks * 256 thr * 8 floats = 2M floats
        int idx = (bx - 4096) * 256 + t;
        f32x4 z = (f32x4){0.f, 0.f, 0.f, 0.f};
        ((f32x4*)out)[2 * idx] = z;
        ((f32x4*)out)[2 * idx + 1] = z;
        return;
    }
    __shared__ float tile[64 * 66];  // pitch 66 breaks bank conflicts
    const int e = bx >> 9;           // 512 blocks/expert = 32 ktiles * 16 ntiles
    const int k0 = ((bx >> 4) & 31) * 64;
    const int n0 = (bx & 15) * 64;
    const float* wsrc = w + (size_t)e * (I_DIM * H_DIM);
#pragma unroll
    for (int r = 0; r < 4; ++r) {
        int kl = (t >> 4) * 4 + r;
        int nl = (t & 15) * 4;
        f32x4 v = *(const f32x4*)(wsrc + (size_t)(k0 + kl) * H_DIM + n0 + nl);
        tile[kl * 66 + nl]     = v.x;
        tile[kl * 66 + nl + 1] = v.y;
        tile[kl * 66 + nl + 2] = v.z;
        tile[kl * 66 + nl + 3] = v.w;
    }
    __syncthreads();
    const int nt = n0 >> 7;
    __bf16* base = bp + (size_t)(e * 8 + nt) * 64 * 4096;
#pragma unroll
    for (int r = 0; r < 4; ++r) {
        int nl = (t >> 4) * 4 + r;
        int klc = (t & 15) * 4;
        int n_rel = nl & 15;
        int u = ((n0 & 127) + nl) >> 4;
        int kb = (k0 + klc) >> 5;
        int quad = (klc >> 3) & 3;
        int j0 = klc & 7;
        bf16x4 b = { (__bf16)tile[klc * 66 + nl],
                     (__bf16)tile[(klc + 1) * 66 + nl],
                     (__bf16)tile[(klc + 2) * 66 + nl],
                     (__bf16)tile[(klc + 3) * 66 + nl] };
        *(bf16x4*)&base[(size_t)kb * 4096 + u * 512 + (quad * 16 + n_rel) * 8 + j0] = b;
    }
}

// Pack A: gather routed rows -> bf16 tiles in fragment order.
// grid (MAX_SLOTS/64, 8): x = unit-group (4 waves = 4 units of 16 slots),
// y = kb-chunk (8 of 64 kbs) -> 640 blocks, plenty of latency-hiding.
__global__ __launch_bounds__(256) void packa_kernel(
    const float* __restrict__ x, const int* __restrict__ cnt,
    const int* __restrict__ rowlist, __bf16* __restrict__ ap) {
    int off[9];
    experts_off(cnt, off);
    const int wave = threadIdx.x >> 6, lane = threadIdx.x & 63;
    const int gu = blockIdx.x * 4 + wave;   // global unit
    const int sb = gu * 16;
    if (sb >= off[8]) return;
    int e = 0;
#pragma unroll
    for (int i = 1; i < 8; ++i) if (sb >= off[i]) e = i;
    const int m_rel = lane & 15, kq = lane >> 4;
    const int local = sb - off[e] + m_rel;
    const bool valid = local < cnt[e];
    const int kb0 = blockIdx.y * 8;
    const float* src = x + (size_t)(valid ? rowlist[e * ROWS + local] : 0) * I_DIM
                         + kb0 * 32 + kq * 8;
    __bf16* dst = ap + (size_t)(sb >> 7) * 64 * 4096 + (size_t)kb0 * 4096
                     + ((sb >> 4) & 7) * 512 + lane * 8;
#pragma unroll
    for (int kb = 0; kb < 8; ++kb) {
        f32x4 lo = *(const f32x4*)(src + kb * 32);
        f32x4 hi = *(const f32x4*)(src + kb * 32 + 4);
        bf16x8 v;
        if (valid) {
            v = (bf16x8){ (__bf16)lo.x, (__bf16)lo.y, (__bf16)lo.z, (__bf16)lo.w,
                          (__bf16)hi.x, (__bf16)hi.y, (__bf16)hi.z, (__bf16)hi.w };
        } else {
            v = (bf16x8){ (__bf16)0.f, (__bf16)0.f, (__bf16)0.f, (__bf16)0.f,
                          (__bf16)0.f, (__bf16)0.f, (__bf16)0.f, (__bf16)0.f };
        }
        *(bf16x8*)(dst + (size_t)kb * 4096) = v;
    }
}

// Grouped expert GEMM, 128x128 tile, bf16 MFMA 16x16x32.
// 4-stage LDS pipeline, DMA issued 3 iters ahead; barrier is a raw
// `s_waitcnt vmcnt(8); s_barrier` (waits only the stage about to be consumed;
// each wave waits its OWN DMAs, barrier joins all producers) -- prefetch
// stays in flight across the barrier, hipBLASLt-style.
__global__ __launch_bounds__(256, 2) void gemm_kernel(
    const __bf16* __restrict__ ap, const __bf16* __restrict__ bp,
    const int* __restrict__ cnt, const int* __restrict__ rowlist,
    const float* __restrict__ topk_w, float* __restrict__ out) {
    int off[9];
    experts_off(cnt, off);
    const int zt = blockIdx.y;
    const int sb = zt * M_TILE;
    if (sb >= off[8]) return;
    int e = 0;
#pragma unroll
    for (int i = 1; i < 8; ++i) if (sb >= off[i]) e = i;
    const int cnt_e = cnt[e];
    const int lm0 = sb - off[e];
    if (lm0 >= cnt_e) return;   // all-padding tile
    const int ntile = blockIdx.x & 7;
    const int khalf = blockIdx.x >> 3;
    const int n0 = ntile * N_TILE;
    const int tid = threadIdx.x;
    const int lane = tid & 63;
    const int wave = tid >> 6;
    const int wm = wave & 1, wn = wave >> 1;

    __shared__ __bf16 As[4][M_TILE * BK];   // 4 x 8 KB
    __shared__ __bf16 Bs[4][N_TILE * BK];   // 4 x 8 KB

    // per-wave DMA: A units {2w,2w+1}, B units {2w,2w+1}
    const __bf16* a_src = ap + ((size_t)zt * 64 + khalf * 32) * 4096
                             + 2 * wave * 512 + lane * 8;
    const __bf16* b_src = bp + ((size_t)(e * 8 + ntile) * 64 + khalf * 32) * 4096
                             + 2 * wave * 512 + lane * 8;
    const int du = 2 * wave * 512;

    f32x4 acc[4][4];
#pragma unroll
    for (int mt = 0; mt < 4; ++mt)
#pragma unroll
        for (int nt = 0; nt < 4; ++nt)
            acc[mt][nt] = (f32x4){0.f, 0.f, 0.f, 0.f};

    auto issue = [&](int itx) {
        const int st = itx & 3;
        const __bf16* as = a_src + (size_t)itx * 4096;
        const __bf16* bs = b_src + (size_t)itx * 4096;
        load_lds16(as,       &As[st][du]);
        load_lds16(as + 512, &As[st][du + 512]);
        load_lds16(bs,       &Bs[st][du]);
        load_lds16(bs + 512, &Bs[st][du + 512]);
    };
    auto compute = [&](int st) {
        bf16x8 bfr[4], af[4];
#pragma unroll
        for (int nt = 0; nt < 4; ++nt)
            bfr[nt] = *(const bf16x8*)&Bs[st][(wn * 4 + nt) * 512 + lane * 8];
#pragma unroll
        for (int mt = 0; mt < 4; ++mt)
            af[mt] = *(const bf16x8*)&As[st][(wm * 4 + mt) * 512 + lane * 8];
#pragma unroll
        for (int mt = 0; mt < 4; ++mt)
#pragma unroll
            for (int nt = 0; nt < 4; ++nt)
                acc[mt][nt] = __builtin_amdgcn_mfma_f32_16x16x32_bf16(
                    af[mt], bfr[nt], acc[mt][nt], 0, 0, 0);
    };

    // prologue: stages 0..2 in flight (12 DMAs/wave)
    issue(0); issue(1); issue(2);

    // steady state: at barrier, 12 outstanding -> vmcnt(8) drains exactly the
    // 4 DMAs of the stage about to be consumed.
    for (int it = 0; it < NITER - 2; ++it) {
        asm volatile("s_waitcnt vmcnt(8)\n\ts_barrier" ::: "memory");
        if (it + 3 < NITER) issue(it + 3);
        compute(it & 3);
    }
    asm volatile("s_waitcnt vmcnt(4)\n\ts_barrier" ::: "memory");
    compute((NITER - 2) & 3);
    asm volatile("s_waitcnt vmcnt(0)\n\ts_barrier" ::: "memory");
    compute((NITER - 1) & 3);

    // epilogue: C/D col=lane&15, row=(lane>>4)*4+reg; scale by topk weight,
    // atomicAdd into out[token] (covers topk-sum and K-split sum)
    const int lq = lane >> 4, ln = lane & 15;
    const int* rl = rowlist + e * ROWS;
#pragma unroll
    for (int mt = 0; mt < 4; ++mt) {
#pragma unroll
        for (int j = 0; j < 4; ++j) {
            int local = lm0 + (wm * 4 + mt) * 16 + lq * 4 + j;
            if (local < cnt_e) {
                int row = rl[local];
                float tw = topk_w[row];
                float* orow = out + (size_t)(row >> 1) * H_DIM + n0 + wn * 64 + ln;
#pragma unroll
                for (int nt = 0; nt < 4; ++nt)
                    atomicAdd(&orow[nt * 16], acc[mt][nt][j] * tw);
            }
        }
    }
}

extern "C" void kernel_launch(void* const* d_in, const int* in_sizes, int n_in,
                              void* d_out, int out_size, void* d_ws, size_t ws_size,
                              hipStream_t stream) {
    const float* x      = (const float*)d_in[0];  // [ROWS, I_DIM] fp32
    const float* w      = (const float*)d_in[1];  // [E, I_DIM, H_DIM] fp32
    const float* logits = (const float*)d_in[2];  // [T, E] fp32
    float* out = (float*)d_out;                   // [T, H_DIM] fp32

    char* ws = (char*)d_ws;
    float*  topk_w  = (float*)ws;                             // 16 KB
    int*    cnt     = (int*)(ws + 16384);                     // 8 int (padded)
    int*    rowlist = (int*)(ws + 16384 + 128);               // 128 KB
    __bf16* bp      = (__bf16*)(ws + 16384 + 128 + 131072);   // packed B (32 MB)
    __bf16* ap      = (__bf16*)(ws + 16384 + 128 + 131072 + (size_t)32 * 1024 * 1024); // packed A (20 MB)

    hipMemsetAsync(cnt, 0, N_EXPERTS * sizeof(int), stream);
    // prep: B transpose+pack (4096) + out zero (1024) + routing (8)
    prep_kernel<<<5128, 256, 0, stream>>>(w, bp, out, logits, topk_w, cnt, rowlist);
    // pack A: (80 unit-groups) x (8 kb-chunks)
    packa_kernel<<<dim3(MAX_SLOTS / 64, 8), 256, 0, stream>>>(x, cnt, rowlist, ap);
    // x = ntile+khalf (16, all active), y = m-tile (early-exit tail)
    gemm_kernel<<<dim3((H_DIM / N_TILE) * KSPLIT, MAX_ZT), 256, 0, stream>>>(
        ap, bp, cnt, rowlist, topk_w, out);
}